// Round 1
// baseline (1406.070 us; speedup 1.0000x reference)
//
#include <hip/hip_runtime.h>
#include <hip/hip_bf16.h>

#define N_NODES_C 100000
#define EMBED_C 64

// ---------------- degree / norm ----------------

__global__ void k_setdeg(float* deg, int N) {
    int i = blockIdx.x * blockDim.x + threadIdx.x;
    if (i < N) deg[i] = 1.0f;   // self-loop
}

__global__ void k_deg(const int* __restrict__ dst, float* deg, int E) {
    int e = blockIdx.x * blockDim.x + threadIdx.x;
    int stride = gridDim.x * blockDim.x;
    for (; e < E; e += stride) atomicAdd(&deg[dst[e]], 1.0f);
}

__global__ void k_dinv(float* deg, int N) {
    int i = blockIdx.x * blockDim.x + threadIdx.x;
    if (i < N) deg[i] = rsqrtf(fmaxf(deg[i], 1.0f));
}

// ---------------- embed GEMM: h = x @ We^T  ([N,128] @ [128,64]^T) ----------------
// block 256 = 4 waves, 32 rows/block (8 rows per wave), lane = output feature.

__global__ __launch_bounds__(256) void k_embed(const float* __restrict__ x,
                                               const float* __restrict__ We,
                                               float* __restrict__ h, int N) {
    __shared__ float Ws[64 * 129];   // padded: bank = (f+k)%32, 2-way free
    __shared__ float xs[32 * 128];
    int tid = threadIdx.x;

#pragma unroll
    for (int i = 0; i < 32; ++i) {
        int m = tid + i * 256;          // 8192 elements
        int f = m >> 7, k = m & 127;
        Ws[f * 129 + k] = We[m];
    }
    int base = blockIdx.x * 32;
    const float4* x4 = (const float4*)(x + (size_t)base * 128);
#pragma unroll
    for (int i = 0; i < 4; ++i) {
        int m = tid + i * 256;          // 1024 float4s
        ((float4*)xs)[m] = x4[m];       // N divisible by 32 -> no guard
    }
    __syncthreads();

    int f = tid & 63, g = tid >> 6;
    float acc[8] = {0, 0, 0, 0, 0, 0, 0, 0};
#pragma unroll 4
    for (int k = 0; k < 128; k += 4) {
        float w0 = Ws[f * 129 + k + 0];
        float w1 = Ws[f * 129 + k + 1];
        float w2 = Ws[f * 129 + k + 2];
        float w3 = Ws[f * 129 + k + 3];
#pragma unroll
        for (int j = 0; j < 8; ++j) {
            const float4 xv = *(const float4*)&xs[(g * 8 + j) * 128 + k];  // wave-broadcast
            acc[j] = fmaf(xv.x, w0, acc[j]);
            acc[j] = fmaf(xv.y, w1, acc[j]);
            acc[j] = fmaf(xv.z, w2, acc[j]);
            acc[j] = fmaf(xv.w, w3, acc[j]);
        }
    }
#pragma unroll
    for (int j = 0; j < 8; ++j) {
        int r = base + g * 8 + j;
        h[(size_t)r * 64 + f] = acc[j];
    }
}

// ---------------- GCN layer GEMM: hw = act(hin) @ Wg^T; hacc = hw*dinv^2 -------
// act(h) = relu(h + bias_prev) if act!=0 else h. hacc may alias hin.

__global__ __launch_bounds__(256) void k_gcn(const float* __restrict__ hin,
                                             const float* __restrict__ Wg,
                                             const float* __restrict__ bias_prev, int act,
                                             const float* __restrict__ dinv,
                                             float* __restrict__ hw,
                                             float* __restrict__ hacc, int N) {
    __shared__ float Ws[64 * 65];
    __shared__ float xs[32 * 64];
    int tid = threadIdx.x;

#pragma unroll
    for (int i = 0; i < 16; ++i) {
        int m = tid + i * 256;          // 4096 elements
        Ws[(m >> 6) * 65 + (m & 63)] = Wg[m];
    }
    int base = blockIdx.x * 32;
    const float4* hin4 = (const float4*)(hin + (size_t)base * 64);
#pragma unroll
    for (int i = 0; i < 2; ++i) {
        int m = tid + i * 256;          // 512 float4s
        float4 v = hin4[m];
        if (act) {
            int kf = (m & 15) * 4;
            v.x = fmaxf(v.x + bias_prev[kf + 0], 0.f);
            v.y = fmaxf(v.y + bias_prev[kf + 1], 0.f);
            v.z = fmaxf(v.z + bias_prev[kf + 2], 0.f);
            v.w = fmaxf(v.w + bias_prev[kf + 3], 0.f);
        }
        ((float4*)xs)[m] = v;
    }
    __syncthreads();

    int f = tid & 63, g = tid >> 6;
    float acc[8] = {0, 0, 0, 0, 0, 0, 0, 0};
#pragma unroll 4
    for (int k = 0; k < 64; k += 4) {
        float w0 = Ws[f * 65 + k + 0];
        float w1 = Ws[f * 65 + k + 1];
        float w2 = Ws[f * 65 + k + 2];
        float w3 = Ws[f * 65 + k + 3];
#pragma unroll
        for (int j = 0; j < 8; ++j) {
            const float4 xv = *(const float4*)&xs[(g * 8 + j) * 64 + k];
            acc[j] = fmaf(xv.x, w0, acc[j]);
            acc[j] = fmaf(xv.y, w1, acc[j]);
            acc[j] = fmaf(xv.z, w2, acc[j]);
            acc[j] = fmaf(xv.w, w3, acc[j]);
        }
    }
#pragma unroll
    for (int j = 0; j < 8; ++j) {
        int r = base + g * 8 + j;
        float di = dinv[r];
        hw[(size_t)r * 64 + f] = acc[j];
        hacc[(size_t)r * 64 + f] = acc[j] * di * di;   // self-loop term
    }
}

// ---------------- edge scatter: hacc[dst] += hw[src] * dinv[src]*dinv[dst] ------
// one wave per edge, lane = feature.

__global__ __launch_bounds__(256) void k_edge(const int* __restrict__ ei,
                                              const float* __restrict__ dinv,
                                              const float* __restrict__ hw,
                                              float* __restrict__ acc, int E) {
    int lane = threadIdx.x & 63;
    int wid = blockIdx.x * (blockDim.x >> 6) + (threadIdx.x >> 6);
    int nw = gridDim.x * (blockDim.x >> 6);
    const int* srcp = ei;
    const int* dstp = ei + E;
    for (int e = wid; e < E; e += nw) {
        int s = srcp[e];
        int d = dstp[e];
        float nrm = dinv[s] * dinv[d];
        float v = hw[(size_t)s * 64 + lane] * nrm;
        atomicAdd(&acc[(size_t)d * 64 + lane], v);
    }
}

// ---------------- centroid distances + pooling ----------------
// block 256: k = tid%128 (centroid id, <100 active), g = tid/128 splits node tile.

__global__ __launch_bounds__(256) void k_cent(const float* __restrict__ hin,
                                              const float* __restrict__ b2,
                                              const float* __restrict__ C,
                                              float* __restrict__ pooled, int N) {
    __shared__ float hs[128 * 64];
    int tid = threadIdx.x;
    int base = blockIdx.x * 128;
    int nn = min(128, N - base);

    const float4* hin4 = (const float4*)(hin + (size_t)base * 64);
#pragma unroll
    for (int i = 0; i < 8; ++i) {
        int m = tid + i * 256;          // 2048 float4s
        int r = m >> 4;
        float4 v;
        if (r < nn) {
            v = hin4[m];
            int kf = (m & 15) * 4;
            v.x = fmaxf(v.x + b2[kf + 0], 0.f);
            v.y = fmaxf(v.y + b2[kf + 1], 0.f);
            v.z = fmaxf(v.z + b2[kf + 2], 0.f);
            v.w = fmaxf(v.w + b2[kf + 3], 0.f);
        } else {
            v.x = v.y = v.z = v.w = 0.f;
        }
        ((float4*)hs)[m] = v;
    }
    __syncthreads();

    int k = tid & 127;
    int g = tid >> 7;
    float creg[64];
    if (k < 100) {
        const float4* c4 = (const float4*)(C + (size_t)k * 64);
#pragma unroll
        for (int i = 0; i < 16; ++i) {
            float4 v = c4[i];
            creg[4 * i + 0] = v.x;
            creg[4 * i + 1] = v.y;
            creg[4 * i + 2] = v.z;
            creg[4 * i + 3] = v.w;
        }
    } else {
#pragma unroll
        for (int i = 0; i < 64; ++i) creg[i] = 0.f;
    }

    float psum = 0.f;
    int lo = g * 64;
    int hi = min(nn, g * 64 + 64);
    for (int node = lo; node < hi; ++node) {
        float d2 = 0.f;
#pragma unroll
        for (int j4 = 0; j4 < 16; ++j4) {
            float4 hv = *(const float4*)&hs[node * 64 + j4 * 4];  // wave-broadcast
            float t;
            t = hv.x - creg[4 * j4 + 0]; d2 = fmaf(t, t, d2);
            t = hv.y - creg[4 * j4 + 1]; d2 = fmaf(t, t, d2);
            t = hv.z - creg[4 * j4 + 2]; d2 = fmaf(t, t, d2);
            t = hv.w - creg[4 * j4 + 3]; d2 = fmaf(t, t, d2);
        }
        psum += sqrtf(d2 + 1e-12f);
    }
    if (k < 100) atomicAdd(&pooled[k], psum);
}

// ---------------- output head ----------------

__global__ void k_out(const float* __restrict__ pooled,
                      const float* __restrict__ Wout,
                      const float* __restrict__ bout,
                      float* __restrict__ out, float invN) {
    int t = threadIdx.x;
    if (t < 10) {
        float s = 0.f;
        for (int k = 0; k < 100; ++k) s += pooled[k] * Wout[t * 100 + k];
        out[t] = s * invN + bout[t];
    }
}

// ---------------- launcher ----------------

extern "C" void kernel_launch(void* const* d_in, const int* in_sizes, int n_in,
                              void* d_out, int out_size, void* d_ws, size_t ws_size,
                              hipStream_t stream) {
    const float* x      = (const float*)d_in[0];
    const int*   ei     = (const int*)d_in[1];
    const float* We     = (const float*)d_in[2];
    const float* Wg     = (const float*)d_in[3];
    const float* bg     = (const float*)d_in[4];
    const float* C      = (const float*)d_in[5];
    const float* Wout   = (const float*)d_in[6];
    const float* bout   = (const float*)d_in[7];
    float*       out    = (float*)d_out;

    const int N = in_sizes[0] / 128;    // 100000
    const int E = in_sizes[1] / 2;      // 1600000

    char* ws = (char*)d_ws;
    float* dinv   = (float*)ws;                                // N floats
    float* hA     = (float*)(ws + 400128);                     // N*64 floats
    float* hB     = (float*)(ws + 400128 + 25600000);          // N*64 floats
    float* pooled = (float*)(ws + 400128 + 2 * 25600000);      // 128 floats

    hipMemsetAsync(pooled, 0, 128 * sizeof(float), stream);

    // degree / dinv
    k_setdeg<<<(N + 255) / 256, 256, 0, stream>>>(dinv, N);
    k_deg<<<4096, 256, 0, stream>>>(ei + E, dinv, E);
    k_dinv<<<(N + 255) / 256, 256, 0, stream>>>(dinv, N);

    // embed
    k_embed<<<N / 32, 256, 0, stream>>>(x, We, hA, N);

    // 3 GCN layers
    for (int l = 0; l < 3; ++l) {
        const float* bias_prev = (l == 0) ? bg : (bg + (l - 1) * 64);
        int act = (l == 0) ? 0 : 1;
        k_gcn<<<N / 32, 256, 0, stream>>>(hA, Wg + (size_t)l * 64 * 64, bias_prev, act,
                                          dinv, hB, hA, N);
        k_edge<<<8192, 256, 0, stream>>>(ei, dinv, hB, hA, E);
    }

    // centroid distances + pooling (applies relu + b_gcn[2])
    k_cent<<<(N + 127) / 128, 256, 0, stream>>>(hA, bg + 2 * 64, C, pooled, N);

    // head
    k_out<<<1, 64, 0, stream>>>(pooled, Wout, bout, out, 1.0f / (float)N);
}

// Round 2
// 803.311 us; speedup vs baseline: 1.7503x; 1.7503x over previous
//
#include <hip/hip_runtime.h>
#include <hip/hip_bf16.h>

// ============ CSR build: histogram -> scan -> fill ============

__global__ void k_hist(const int* __restrict__ dst, int* __restrict__ counts, int E) {
    int e = blockIdx.x * blockDim.x + threadIdx.x;
    int stride = gridDim.x * blockDim.x;
    for (; e < E; e += stride) atomicAdd(&counts[dst[e]], 1);
}

__global__ void k_dinv(const int* __restrict__ counts, float* __restrict__ dinv, int N) {
    int i = blockIdx.x * blockDim.x + threadIdx.x;
    if (i < N) dinv[i] = rsqrtf((float)(counts[i] + 1));   // +1 self loop
}

// exclusive scan, 3-phase
__global__ void k_scan1(const int* __restrict__ counts, int* __restrict__ rowptr,
                        int* __restrict__ bsum, int N) {
    __shared__ int tmp[256];
    int i = blockIdx.x * 256 + threadIdx.x;
    int v = (i < N) ? counts[i] : 0;
    tmp[threadIdx.x] = v;
    __syncthreads();
    for (int off = 1; off < 256; off <<= 1) {
        int t = (threadIdx.x >= off) ? tmp[threadIdx.x - off] : 0;
        __syncthreads();
        tmp[threadIdx.x] += t;
        __syncthreads();
    }
    if (i < N) rowptr[i] = tmp[threadIdx.x] - v;  // exclusive within block
    if (threadIdx.x == 255) bsum[blockIdx.x] = tmp[255];
}

__global__ void k_scan2(int* bsum, int nb) {
    if (threadIdx.x == 0) {
        int acc = 0;
        for (int b = 0; b < nb; ++b) { int v = bsum[b]; bsum[b] = acc; acc += v; }
    }
}

__global__ void k_scan3(int* __restrict__ rowptr, const int* __restrict__ bsum, int N) {
    int i = blockIdx.x * 256 + threadIdx.x;
    if (i < N) rowptr[i] += bsum[blockIdx.x];
}

__global__ void k_fill(const int* __restrict__ ei, const float* __restrict__ dinv,
                       const int* __restrict__ rowptr, int* __restrict__ cursor,
                       int* __restrict__ ssrc, float* __restrict__ snrm, int E) {
    int e = blockIdx.x * blockDim.x + threadIdx.x;
    int stride = gridDim.x * blockDim.x;
    const int* srcp = ei;
    const int* dstp = ei + E;
    for (; e < E; e += stride) {
        int s = srcp[e];
        int d = dstp[e];
        int p = rowptr[d] + atomicAdd(&cursor[d], 1);
        ssrc[p] = s;
        snrm[p] = dinv[s] * dinv[d];
    }
}

// ============ embed GEMM: h = x @ We^T ([N,128] @ [128,64]^T) ============
// block 256 = 4 waves, 32 rows/block (8 rows per wave), lane = output feature.

__global__ __launch_bounds__(256) void k_embed(const float* __restrict__ x,
                                               const float* __restrict__ We,
                                               float* __restrict__ h, int N) {
    __shared__ float Ws[64 * 129];
    __shared__ float xs[32 * 128];
    int tid = threadIdx.x;

#pragma unroll
    for (int i = 0; i < 32; ++i) {
        int m = tid + i * 256;
        Ws[(m >> 7) * 129 + (m & 127)] = We[m];
    }
    int base = blockIdx.x * 32;
    const float4* x4 = (const float4*)(x + (size_t)base * 128);
#pragma unroll
    for (int i = 0; i < 4; ++i) {
        int m = tid + i * 256;
        ((float4*)xs)[m] = x4[m];
    }
    __syncthreads();

    int f = tid & 63, g = tid >> 6;
    float acc[8] = {0, 0, 0, 0, 0, 0, 0, 0};
#pragma unroll 4
    for (int k = 0; k < 128; k += 4) {
        float w0 = Ws[f * 129 + k + 0];
        float w1 = Ws[f * 129 + k + 1];
        float w2 = Ws[f * 129 + k + 2];
        float w3 = Ws[f * 129 + k + 3];
#pragma unroll
        for (int j = 0; j < 8; ++j) {
            const float4 xv = *(const float4*)&xs[(g * 8 + j) * 128 + k];
            acc[j] = fmaf(xv.x, w0, acc[j]);
            acc[j] = fmaf(xv.y, w1, acc[j]);
            acc[j] = fmaf(xv.z, w2, acc[j]);
            acc[j] = fmaf(xv.w, w3, acc[j]);
        }
    }
#pragma unroll
    for (int j = 0; j < 8; ++j) {
        int r = base + g * 8 + j;
        h[(size_t)r * 64 + f] = acc[j];
    }
}

// ============ GCN layer GEMM: hw = act(hin) @ Wg^T ============

__global__ __launch_bounds__(256) void k_gcn(const float* __restrict__ hin,
                                             const float* __restrict__ Wg,
                                             const float* __restrict__ bias_prev, int act,
                                             float* __restrict__ hw, int N) {
    __shared__ float Ws[64 * 65];
    __shared__ float xs[32 * 64];
    int tid = threadIdx.x;

#pragma unroll
    for (int i = 0; i < 16; ++i) {
        int m = tid + i * 256;
        Ws[(m >> 6) * 65 + (m & 63)] = Wg[m];
    }
    int base = blockIdx.x * 32;
    const float4* hin4 = (const float4*)(hin + (size_t)base * 64);
#pragma unroll
    for (int i = 0; i < 2; ++i) {
        int m = tid + i * 256;
        float4 v = hin4[m];
        if (act) {
            int kf = (m & 15) * 4;
            v.x = fmaxf(v.x + bias_prev[kf + 0], 0.f);
            v.y = fmaxf(v.y + bias_prev[kf + 1], 0.f);
            v.z = fmaxf(v.z + bias_prev[kf + 2], 0.f);
            v.w = fmaxf(v.w + bias_prev[kf + 3], 0.f);
        }
        ((float4*)xs)[m] = v;
    }
    __syncthreads();

    int f = tid & 63, g = tid >> 6;
    float acc[8] = {0, 0, 0, 0, 0, 0, 0, 0};
#pragma unroll 4
    for (int k = 0; k < 64; k += 4) {
        float w0 = Ws[f * 65 + k + 0];
        float w1 = Ws[f * 65 + k + 1];
        float w2 = Ws[f * 65 + k + 2];
        float w3 = Ws[f * 65 + k + 3];
#pragma unroll
        for (int j = 0; j < 8; ++j) {
            const float4 xv = *(const float4*)&xs[(g * 8 + j) * 64 + k];
            acc[j] = fmaf(xv.x, w0, acc[j]);
            acc[j] = fmaf(xv.y, w1, acc[j]);
            acc[j] = fmaf(xv.z, w2, acc[j]);
            acc[j] = fmaf(xv.w, w3, acc[j]);
        }
    }
#pragma unroll
    for (int j = 0; j < 8; ++j) {
        int r = base + g * 8 + j;
        hw[(size_t)r * 64 + f] = acc[j];
    }
}

// ============ CSR gather-aggregate: one wave per dst node ============
// out[d] = hw[d]*dinv[d]^2 + sum_{e in row d} hw[src_e] * nrm_e

__global__ __launch_bounds__(256) void k_agg(const int* __restrict__ rowptr,
                                             const int* __restrict__ counts,
                                             const int* __restrict__ ssrc,
                                             const float* __restrict__ snrm,
                                             const float* __restrict__ dinv,
                                             const float* __restrict__ hw,
                                             float* __restrict__ out, int N) {
    int lane = threadIdx.x & 63;
    int d = blockIdx.x * 4 + (threadIdx.x >> 6);
    if (d >= N) return;

    float di = dinv[d];
    float acc = hw[(size_t)d * 64 + lane] * di * di;   // self loop

    int beg = rowptr[d];
    int cnt = counts[d];
    for (int base = 0; base < cnt; base += 64) {
        int m = min(64, cnt - base);
        int s = 0;
        float nr = 0.f;
        if (lane < m) {
            s = ssrc[beg + base + lane];
            nr = snrm[beg + base + lane];
        }
        for (int j = 0; j < m; ++j) {
            int sj = __shfl(s, j);
            float nj = __shfl(nr, j);
            acc = fmaf(hw[(size_t)sj * 64 + lane], nj, acc);
        }
    }
    out[(size_t)d * 64 + lane] = acc;
}

// ============ centroid distances + pooling ============

__global__ __launch_bounds__(256) void k_cent(const float* __restrict__ hin,
                                              const float* __restrict__ b2,
                                              const float* __restrict__ C,
                                              float* __restrict__ pooled, int N) {
    __shared__ float hs[128 * 64];
    int tid = threadIdx.x;
    int base = blockIdx.x * 128;
    int nn = min(128, N - base);

    const float4* hin4 = (const float4*)(hin + (size_t)base * 64);
#pragma unroll
    for (int i = 0; i < 8; ++i) {
        int m = tid + i * 256;
        int r = m >> 4;
        float4 v;
        if (r < nn) {
            v = hin4[m];
            int kf = (m & 15) * 4;
            v.x = fmaxf(v.x + b2[kf + 0], 0.f);
            v.y = fmaxf(v.y + b2[kf + 1], 0.f);
            v.z = fmaxf(v.z + b2[kf + 2], 0.f);
            v.w = fmaxf(v.w + b2[kf + 3], 0.f);
        } else {
            v.x = v.y = v.z = v.w = 0.f;
        }
        ((float4*)hs)[m] = v;
    }
    __syncthreads();

    int k = tid & 127;
    int g = tid >> 7;
    float creg[64];
    if (k < 100) {
        const float4* c4 = (const float4*)(C + (size_t)k * 64);
#pragma unroll
        for (int i = 0; i < 16; ++i) {
            float4 v = c4[i];
            creg[4 * i + 0] = v.x;
            creg[4 * i + 1] = v.y;
            creg[4 * i + 2] = v.z;
            creg[4 * i + 3] = v.w;
        }
    } else {
#pragma unroll
        for (int i = 0; i < 64; ++i) creg[i] = 0.f;
    }

    float psum = 0.f;
    int lo = g * 64;
    int hi = min(nn, g * 64 + 64);
    for (int node = lo; node < hi; ++node) {
        float d2 = 0.f;
#pragma unroll
        for (int j4 = 0; j4 < 16; ++j4) {
            float4 hv = *(const float4*)&hs[node * 64 + j4 * 4];
            float t;
            t = hv.x - creg[4 * j4 + 0]; d2 = fmaf(t, t, d2);
            t = hv.y - creg[4 * j4 + 1]; d2 = fmaf(t, t, d2);
            t = hv.z - creg[4 * j4 + 2]; d2 = fmaf(t, t, d2);
            t = hv.w - creg[4 * j4 + 3]; d2 = fmaf(t, t, d2);
        }
        psum += sqrtf(d2 + 1e-12f);
    }
    if (k < 100) atomicAdd(&pooled[k], psum);
}

// ============ output head ============

__global__ void k_out(const float* __restrict__ pooled,
                      const float* __restrict__ Wout,
                      const float* __restrict__ bout,
                      float* __restrict__ out, float invN) {
    int t = threadIdx.x;
    if (t < 10) {
        float s = 0.f;
        for (int k = 0; k < 100; ++k) s += pooled[k] * Wout[t * 100 + k];
        out[t] = s * invN + bout[t];
    }
}

// ============ launcher ============

extern "C" void kernel_launch(void* const* d_in, const int* in_sizes, int n_in,
                              void* d_out, int out_size, void* d_ws, size_t ws_size,
                              hipStream_t stream) {
    const float* x    = (const float*)d_in[0];
    const int*   ei   = (const int*)d_in[1];
    const float* We   = (const float*)d_in[2];
    const float* Wg   = (const float*)d_in[3];
    const float* bg   = (const float*)d_in[4];
    const float* C    = (const float*)d_in[5];
    const float* Wout = (const float*)d_in[6];
    const float* bout = (const float*)d_in[7];
    float*       out  = (float*)d_out;

    const int N = in_sizes[0] / 128;    // 100000
    const int E = in_sizes[1] / 2;      // 1600000
    const int NB = (N + 255) / 256;     // scan blocks (391)

    char* ws = (char*)d_ws;
    size_t off = 0;
    auto alloc = [&](size_t bytes) { void* p = ws + off; off += (bytes + 511) & ~(size_t)511; return p; };
    float* dinv   = (float*)alloc((size_t)N * 4);
    int*   counts = (int*)  alloc((size_t)N * 4);
    int*   cursor = (int*)  alloc((size_t)N * 4);
    int*   rowptr = (int*)  alloc((size_t)N * 4);
    int*   bsum   = (int*)  alloc((size_t)NB * 4);
    int*   ssrc   = (int*)  alloc((size_t)E * 4);
    float* snrm   = (float*)alloc((size_t)E * 4);
    float* hA     = (float*)alloc((size_t)N * 64 * 4);
    float* hB     = (float*)alloc((size_t)N * 64 * 4);
    float* pooled = (float*)alloc(512);

    hipMemsetAsync(counts, 0, (size_t)N * 4, stream);
    hipMemsetAsync(cursor, 0, (size_t)N * 4, stream);
    hipMemsetAsync(pooled, 0, 512, stream);

    // CSR build
    k_hist<<<4096, 256, 0, stream>>>(ei + E, counts, E);
    k_dinv<<<NB, 256, 0, stream>>>(counts, dinv, N);
    k_scan1<<<NB, 256, 0, stream>>>(counts, rowptr, bsum, N);
    k_scan2<<<1, 64, 0, stream>>>(bsum, NB);
    k_scan3<<<NB, 256, 0, stream>>>(rowptr, bsum, N);
    k_fill<<<4096, 256, 0, stream>>>(ei, dinv, rowptr, cursor, ssrc, snrm, E);

    // embed
    k_embed<<<N / 32, 256, 0, stream>>>(x, We, hA, N);

    // 3 GCN layers: gemm (hA->hB), aggregate (hB->hA)
    for (int l = 0; l < 3; ++l) {
        const float* bias_prev = (l == 0) ? bg : (bg + (l - 1) * 64);
        int act = (l == 0) ? 0 : 1;
        k_gcn<<<N / 32, 256, 0, stream>>>(hA, Wg + (size_t)l * 64 * 64, bias_prev, act, hB, N);
        k_agg<<<(N + 3) / 4, 256, 0, stream>>>(rowptr, counts, ssrc, snrm, dinv, hB, hA, N);
    }

    // centroid distances + pooling (applies relu + b_gcn[2])
    k_cent<<<(N + 127) / 128, 256, 0, stream>>>(hA, bg + 2 * 64, C, pooled, N);

    // head
    k_out<<<1, 64, 0, stream>>>(pooled, Wout, bout, out, 1.0f / (float)N);
}

// Round 3
// 663.952 us; speedup vs baseline: 2.1177x; 1.2099x over previous
//
#include <hip/hip_runtime.h>
#include <hip/hip_bf16.h>

// ============ CSR build: histogram -> scan -> fill ============

__global__ void k_hist(const int* __restrict__ dst, int* __restrict__ counts, int E) {
    int e = blockIdx.x * blockDim.x + threadIdx.x;
    int stride = gridDim.x * blockDim.x;
    for (; e < E; e += stride) atomicAdd(&counts[dst[e]], 1);
}

__global__ void k_dinv(const int* __restrict__ counts, float* __restrict__ dinv, int N) {
    int i = blockIdx.x * blockDim.x + threadIdx.x;
    if (i < N) dinv[i] = rsqrtf((float)(counts[i] + 1));   // +1 self loop
}

// exclusive scan, 3-phase
__global__ void k_scan1(const int* __restrict__ counts, int* __restrict__ rowptr,
                        int* __restrict__ bsum, int N) {
    __shared__ int tmp[256];
    int i = blockIdx.x * 256 + threadIdx.x;
    int v = (i < N) ? counts[i] : 0;
    tmp[threadIdx.x] = v;
    __syncthreads();
    for (int off = 1; off < 256; off <<= 1) {
        int t = (threadIdx.x >= off) ? tmp[threadIdx.x - off] : 0;
        __syncthreads();
        tmp[threadIdx.x] += t;
        __syncthreads();
    }
    if (i < N) rowptr[i] = tmp[threadIdx.x] - v;  // exclusive within block
    if (threadIdx.x == 255) bsum[blockIdx.x] = tmp[255];
}

// parallel exclusive scan of block sums (nb <= 512)
__global__ void k_scan2(int* bsum, int nb) {
    __shared__ int tmp[512];
    int t = threadIdx.x;
    int v = (t < nb) ? bsum[t] : 0;
    tmp[t] = v;
    __syncthreads();
    for (int off = 1; off < 512; off <<= 1) {
        int u = (t >= off) ? tmp[t - off] : 0;
        __syncthreads();
        tmp[t] += u;
        __syncthreads();
    }
    if (t < nb) bsum[t] = tmp[t] - v;   // exclusive
}

__global__ void k_scan3(int* __restrict__ rowptr, const int* __restrict__ bsum, int N) {
    int i = blockIdx.x * 256 + threadIdx.x;
    if (i < N) rowptr[i] += bsum[blockIdx.x];
}

// fill packed (src, nrm) pairs sorted by dst; cursor pre-initialized to rowptr copy
__global__ void k_fill(const int* __restrict__ ei, const float* __restrict__ dinv,
                       int* __restrict__ cursor, int2* __restrict__ epair, int E) {
    int e = blockIdx.x * blockDim.x + threadIdx.x;
    int stride = gridDim.x * blockDim.x;
    const int* srcp = ei;
    const int* dstp = ei + E;
    for (; e < E; e += stride) {
        int s = srcp[e];
        int d = dstp[e];
        int p = atomicAdd(&cursor[d], 1);
        epair[p] = make_int2(s, __float_as_int(dinv[s] * dinv[d]));
    }
}

// ============ embed GEMM: h = x @ We^T ([N,128] @ [128,64]^T) ============

__global__ __launch_bounds__(256) void k_embed(const float* __restrict__ x,
                                               const float* __restrict__ We,
                                               float* __restrict__ h, int N) {
    __shared__ float Ws[64 * 129];
    __shared__ float xs[32 * 128];
    int tid = threadIdx.x;

#pragma unroll
    for (int i = 0; i < 32; ++i) {
        int m = tid + i * 256;
        Ws[(m >> 7) * 129 + (m & 127)] = We[m];
    }
    int base = blockIdx.x * 32;
    const float4* x4 = (const float4*)(x + (size_t)base * 128);
#pragma unroll
    for (int i = 0; i < 4; ++i) {
        int m = tid + i * 256;
        ((float4*)xs)[m] = x4[m];
    }
    __syncthreads();

    int f = tid & 63, g = tid >> 6;
    float acc[8] = {0, 0, 0, 0, 0, 0, 0, 0};
#pragma unroll 4
    for (int k = 0; k < 128; k += 4) {
        float w0 = Ws[f * 129 + k + 0];
        float w1 = Ws[f * 129 + k + 1];
        float w2 = Ws[f * 129 + k + 2];
        float w3 = Ws[f * 129 + k + 3];
#pragma unroll
        for (int j = 0; j < 8; ++j) {
            const float4 xv = *(const float4*)&xs[(g * 8 + j) * 128 + k];
            acc[j] = fmaf(xv.x, w0, acc[j]);
            acc[j] = fmaf(xv.y, w1, acc[j]);
            acc[j] = fmaf(xv.z, w2, acc[j]);
            acc[j] = fmaf(xv.w, w3, acc[j]);
        }
    }
#pragma unroll
    for (int j = 0; j < 8; ++j) {
        int r = base + g * 8 + j;
        h[(size_t)r * 64 + f] = acc[j];
    }
}

// ============ GCN layer GEMM: hw = act(hin) @ Wg^T ============

__global__ __launch_bounds__(256) void k_gcn(const float* __restrict__ hin,
                                             const float* __restrict__ Wg,
                                             const float* __restrict__ bias_prev, int act,
                                             float* __restrict__ hw, int N) {
    __shared__ float Ws[64 * 65];
    __shared__ float xs[32 * 64];
    int tid = threadIdx.x;

#pragma unroll
    for (int i = 0; i < 16; ++i) {
        int m = tid + i * 256;
        Ws[(m >> 6) * 65 + (m & 63)] = Wg[m];
    }
    int base = blockIdx.x * 32;
    const float4* hin4 = (const float4*)(hin + (size_t)base * 64);
#pragma unroll
    for (int i = 0; i < 2; ++i) {
        int m = tid + i * 256;
        float4 v = hin4[m];
        if (act) {
            int kf = (m & 15) * 4;
            v.x = fmaxf(v.x + bias_prev[kf + 0], 0.f);
            v.y = fmaxf(v.y + bias_prev[kf + 1], 0.f);
            v.z = fmaxf(v.z + bias_prev[kf + 2], 0.f);
            v.w = fmaxf(v.w + bias_prev[kf + 3], 0.f);
        }
        ((float4*)xs)[m] = v;
    }
    __syncthreads();

    int f = tid & 63, g = tid >> 6;
    float acc[8] = {0, 0, 0, 0, 0, 0, 0, 0};
#pragma unroll 4
    for (int k = 0; k < 64; k += 4) {
        float w0 = Ws[f * 65 + k + 0];
        float w1 = Ws[f * 65 + k + 1];
        float w2 = Ws[f * 65 + k + 2];
        float w3 = Ws[f * 65 + k + 3];
#pragma unroll
        for (int j = 0; j < 8; ++j) {
            const float4 xv = *(const float4*)&xs[(g * 8 + j) * 64 + k];
            acc[j] = fmaf(xv.x, w0, acc[j]);
            acc[j] = fmaf(xv.y, w1, acc[j]);
            acc[j] = fmaf(xv.z, w2, acc[j]);
            acc[j] = fmaf(xv.w, w3, acc[j]);
        }
    }
#pragma unroll
    for (int j = 0; j < 8; ++j) {
        int r = base + g * 8 + j;
        hw[(size_t)r * 64 + f] = acc[j];
    }
}

// ============ CSR gather-aggregate: one wave per dst node, 4-way MLP ============
// out[d] = hw[d]*dinv[d]^2 + sum_{e in row d} hw[src_e] * nrm_e

__global__ __launch_bounds__(256) void k_agg(const int* __restrict__ rowptr,
                                             const int* __restrict__ counts,
                                             const int2* __restrict__ epair,
                                             const float* __restrict__ dinv,
                                             const float* __restrict__ hw,
                                             float* __restrict__ out, int N) {
    int lane = threadIdx.x & 63;
    int d = blockIdx.x * 4 + (threadIdx.x >> 6);
    if (d >= N) return;

    float di = dinv[d];
    float a0 = hw[(size_t)d * 64 + lane] * di * di;   // self loop
    float a1 = 0.f, a2 = 0.f, a3 = 0.f;

    int beg = rowptr[d];
    int cnt = counts[d];
    for (int base = 0; base < cnt; base += 64) {
        int m = min(64, cnt - base);
        int2 ep = make_int2(0, 0);
        if (lane < m) ep = epair[beg + base + lane];
        int j = 0;
        for (; j + 3 < m; j += 4) {
            int   s0 = __shfl(ep.x, j + 0); float n0 = __int_as_float(__shfl(ep.y, j + 0));
            int   s1 = __shfl(ep.x, j + 1); float n1 = __int_as_float(__shfl(ep.y, j + 1));
            int   s2 = __shfl(ep.x, j + 2); float n2 = __int_as_float(__shfl(ep.y, j + 2));
            int   s3 = __shfl(ep.x, j + 3); float n3 = __int_as_float(__shfl(ep.y, j + 3));
            float h0 = hw[(size_t)s0 * 64 + lane];   // 4 independent gathers in flight
            float h1 = hw[(size_t)s1 * 64 + lane];
            float h2 = hw[(size_t)s2 * 64 + lane];
            float h3 = hw[(size_t)s3 * 64 + lane];
            a0 = fmaf(h0, n0, a0);
            a1 = fmaf(h1, n1, a1);
            a2 = fmaf(h2, n2, a2);
            a3 = fmaf(h3, n3, a3);
        }
        for (; j < m; ++j) {
            int sj = __shfl(ep.x, j);
            float nj = __int_as_float(__shfl(ep.y, j));
            a0 = fmaf(hw[(size_t)sj * 64 + lane], nj, a0);
        }
    }
    out[(size_t)d * 64 + lane] = (a0 + a1) + (a2 + a3);
}

// ============ centroid distances + pooling ============

__global__ __launch_bounds__(256) void k_cent(const float* __restrict__ hin,
                                              const float* __restrict__ b2,
                                              const float* __restrict__ C,
                                              float* __restrict__ pooled, int N) {
    __shared__ float hs[128 * 64];
    int tid = threadIdx.x;
    int base = blockIdx.x * 128;
    int nn = min(128, N - base);

    const float4* hin4 = (const float4*)(hin + (size_t)base * 64);
#pragma unroll
    for (int i = 0; i < 8; ++i) {
        int m = tid + i * 256;
        int r = m >> 4;
        float4 v;
        if (r < nn) {
            v = hin4[m];
            int kf = (m & 15) * 4;
            v.x = fmaxf(v.x + b2[kf + 0], 0.f);
            v.y = fmaxf(v.y + b2[kf + 1], 0.f);
            v.z = fmaxf(v.z + b2[kf + 2], 0.f);
            v.w = fmaxf(v.w + b2[kf + 3], 0.f);
        } else {
            v.x = v.y = v.z = v.w = 0.f;
        }
        ((float4*)hs)[m] = v;
    }
    __syncthreads();

    int k = tid & 127;
    int g = tid >> 7;
    float creg[64];
    if (k < 100) {
        const float4* c4 = (const float4*)(C + (size_t)k * 64);
#pragma unroll
        for (int i = 0; i < 16; ++i) {
            float4 v = c4[i];
            creg[4 * i + 0] = v.x;
            creg[4 * i + 1] = v.y;
            creg[4 * i + 2] = v.z;
            creg[4 * i + 3] = v.w;
        }
    } else {
#pragma unroll
        for (int i = 0; i < 64; ++i) creg[i] = 0.f;
    }

    float psum = 0.f;
    int lo = g * 64;
    int hi = min(nn, g * 64 + 64);
    for (int node = lo; node < hi; ++node) {
        float d2 = 0.f;
#pragma unroll
        for (int j4 = 0; j4 < 16; ++j4) {
            float4 hv = *(const float4*)&hs[node * 64 + j4 * 4];
            float t;
            t = hv.x - creg[4 * j4 + 0]; d2 = fmaf(t, t, d2);
            t = hv.y - creg[4 * j4 + 1]; d2 = fmaf(t, t, d2);
            t = hv.z - creg[4 * j4 + 2]; d2 = fmaf(t, t, d2);
            t = hv.w - creg[4 * j4 + 3]; d2 = fmaf(t, t, d2);
        }
        psum += sqrtf(d2 + 1e-12f);
    }
    if (k < 100) atomicAdd(&pooled[k], psum);
}

// ============ output head ============

__global__ void k_out(const float* __restrict__ pooled,
                      const float* __restrict__ Wout,
                      const float* __restrict__ bout,
                      float* __restrict__ out, float invN) {
    int t = threadIdx.x;
    if (t < 10) {
        float s = 0.f;
        for (int k = 0; k < 100; ++k) s += pooled[k] * Wout[t * 100 + k];
        out[t] = s * invN + bout[t];
    }
}

// ============ launcher ============

extern "C" void kernel_launch(void* const* d_in, const int* in_sizes, int n_in,
                              void* d_out, int out_size, void* d_ws, size_t ws_size,
                              hipStream_t stream) {
    const float* x    = (const float*)d_in[0];
    const int*   ei   = (const int*)d_in[1];
    const float* We   = (const float*)d_in[2];
    const float* Wg   = (const float*)d_in[3];
    const float* bg   = (const float*)d_in[4];
    const float* C    = (const float*)d_in[5];
    const float* Wout = (const float*)d_in[6];
    const float* bout = (const float*)d_in[7];
    float*       out  = (float*)d_out;

    const int N = in_sizes[0] / 128;    // 100000
    const int E = in_sizes[1] / 2;      // 1600000
    const int NB = (N + 255) / 256;     // scan blocks (391)

    char* ws = (char*)d_ws;
    size_t off = 0;
    auto alloc = [&](size_t bytes) { void* p = ws + off; off += (bytes + 511) & ~(size_t)511; return p; };
    float* dinv   = (float*)alloc((size_t)N * 4);
    int*   counts = (int*)  alloc((size_t)N * 4);
    int*   cursor = (int*)  alloc((size_t)N * 4);
    int*   rowptr = (int*)  alloc((size_t)N * 4);
    int*   bsum   = (int*)  alloc((size_t)NB * 4);
    int2*  epair  = (int2*) alloc((size_t)E * 8);
    float* hA     = (float*)alloc((size_t)N * 64 * 4);
    float* hB     = (float*)alloc((size_t)N * 64 * 4);
    float* pooled = (float*)alloc(512);

    hipMemsetAsync(counts, 0, (size_t)N * 4, stream);
    hipMemsetAsync(pooled, 0, 512, stream);

    // CSR build
    k_hist<<<4096, 256, 0, stream>>>(ei + E, counts, E);
    k_dinv<<<NB, 256, 0, stream>>>(counts, dinv, N);
    k_scan1<<<NB, 256, 0, stream>>>(counts, rowptr, bsum, N);
    k_scan2<<<1, 512, 0, stream>>>(bsum, NB);
    k_scan3<<<NB, 256, 0, stream>>>(rowptr, bsum, N);
    hipMemcpyAsync(cursor, rowptr, (size_t)N * 4, hipMemcpyDeviceToDevice, stream);
    k_fill<<<4096, 256, 0, stream>>>(ei, dinv, cursor, epair, E);

    // embed
    k_embed<<<N / 32, 256, 0, stream>>>(x, We, hA, N);

    // 3 GCN layers: gemm (hA->hB), aggregate (hB->hA)
    for (int l = 0; l < 3; ++l) {
        const float* bias_prev = (l == 0) ? bg : (bg + (l - 1) * 64);
        int act = (l == 0) ? 0 : 1;
        k_gcn<<<N / 32, 256, 0, stream>>>(hA, Wg + (size_t)l * 64 * 64, bias_prev, act, hB, N);
        k_agg<<<(N + 3) / 4, 256, 0, stream>>>(rowptr, counts, epair, dinv, hB, hA, N);
    }

    // centroid distances + pooling (applies relu + b_gcn[2])
    k_cent<<<(N + 127) / 128, 256, 0, stream>>>(hA, bg + 2 * 64, C, pooled, N);

    // head
    k_out<<<1, 64, 0, stream>>>(pooled, Wout, bout, out, 1.0f / (float)N);
}